// Round 5
// baseline (667.416 us; speedup 1.0000x reference)
//
#include <hip/hip_runtime.h>
#include <hip/hip_cooperative_groups.h>
#include <math.h>

namespace cg = cooperative_groups;

// Problem constants (fixed by reference).
#define TOKENS      16384     // 8 * 2048
#define HID         2048
#define EXPERTS     64
#define CAPSLOT     1024      // per-expert list cap; counts ~Binom(16384,1/64)=256±16
#define CAP         512       // expert_capacity = 2*ceil(16384/64)
#define TPW         8         // tokens per wave
#define KT          8         // k-tile per inner step
#define GRID_BLKS   512       // 512 blocks x 4 waves x 8 tokens = 16384 tokens

// ---------------------------------------------------------------------------
// Single fused cooperative kernel.
// Phase A: logits GEMM (lane=expert: W coalesced vector loads, x wave-uniform
//          scalar loads) + softmax/top1/top2 + per-expert list build.
// Phase B: per-expert batch-prioritized ranking -> keep flags (blocks 0..63).
// Phase C: materialize [top_1_mask | gates], coalesced float4 stores.
// ---------------------------------------------------------------------------
__global__ __launch_bounds__(256) void k_fused(
    const float* __restrict__ x, const float* __restrict__ W,
    float* __restrict__ out,
    float* __restrict__ p1o, float* __restrict__ p2o,
    int* __restrict__ top1o, int* __restrict__ top2o,
    int* __restrict__ count1, int* __restrict__ count2,
    int* __restrict__ list1, int* __restrict__ list2,
    int* __restrict__ keep1, int* __restrict__ keep2)
{
    __shared__ float skey[CAPSLOT];
    __shared__ int   stok[CAPSLOT];

    cg::grid_group grid = cg::this_grid();
    const int tid  = threadIdx.x;
    const int lane = tid & 63;                                   // expert id
    const int wv   = __builtin_amdgcn_readfirstlane(tid >> 6);   // wave 0..3

    // ---- phase 0: zero per-expert counters (ws is poisoned each launch) ----
    if (blockIdx.x == 0) {
        if (tid < EXPERTS)                 count1[tid] = 0;
        else if (tid < 2 * EXPERTS)        count2[tid - EXPERTS] = 0;
    }
    grid.sync();

    // =======================================================================
    // Phase A: GEMM + routing. Wave = 64 expert-lanes x TPW tokens, full K.
    // =======================================================================
    {
        const int t0 = blockIdx.x * (4 * TPW) + wv * TPW;        // uniform

        float acc[TPW];
        #pragma unroll
        for (int t = 0; t < TPW; ++t) acc[t] = 0.f;

        for (int k0 = 0; k0 < HID; k0 += KT) {
            // W column slice: per-lane, coalesced b32 (vmcnt-pipelined)
            float wr[KT];
            #pragma unroll
            for (int kk = 0; kk < KT; ++kk)
                wr[kk] = W[(k0 + kk) * EXPERTS + lane];

            // x: wave-uniform addresses -> scalar loads (SGPRs)
            #pragma unroll
            for (int t = 0; t < TPW; ++t) {
                const float* xp = x + (size_t)(t0 + t) * HID + k0;
                const float4 xa = *(const float4*)xp;
                const float4 xb = *(const float4*)(xp + 4);
                acc[t] = fmaf(xa.x, wr[0], acc[t]);
                acc[t] = fmaf(xa.y, wr[1], acc[t]);
                acc[t] = fmaf(xa.z, wr[2], acc[t]);
                acc[t] = fmaf(xa.w, wr[3], acc[t]);
                acc[t] = fmaf(xb.x, wr[4], acc[t]);
                acc[t] = fmaf(xb.y, wr[5], acc[t]);
                acc[t] = fmaf(xb.z, wr[6], acc[t]);
                acc[t] = fmaf(xb.w, wr[7], acc[t]);
            }
        }

        // per-token routing: 64-wide cross-lane reductions, lane = expert
        #pragma unroll
        for (int t = 0; t < TPW; ++t) {
            const int token = t0 + t;
            const float logit = acc[t];

            // top-1 argmax, first-index tie-break
            float bv = logit; int be = lane;
            #pragma unroll
            for (int m = 32; m >= 1; m >>= 1) {
                float ov = __shfl_xor(bv, m);
                int   oe = __shfl_xor(be, m);
                if (ov > bv || (ov == bv && oe < be)) { bv = ov; be = oe; }
            }
            const float m1 = bv;
            const int   e1 = be;

            // top-2: argmax excluding e1
            float bv2 = (lane == e1) ? -INFINITY : logit;
            int   be2 = (lane == e1) ? (1 << 30) : lane;
            #pragma unroll
            for (int m = 32; m >= 1; m >>= 1) {
                float ov = __shfl_xor(bv2, m);
                int   oe = __shfl_xor(be2, m);
                if (ov > bv2 || (ov == bv2 && oe < be2)) { bv2 = ov; be2 = oe; }
            }
            const int e2 = be2;

            // softmax denominator (max-subtracted)
            float s = expf(logit - m1);
            #pragma unroll
            for (int m = 32; m >= 1; m >>= 1) s += __shfl_xor(s, m);

            if (lane == 0) {
                p1o[token]   = 1.0f / s;
                p2o[token]   = expf(bv2 - m1) / s;
                top1o[token] = e1;
                top2o[token] = e2;
                int s1 = atomicAdd(&count1[e1], 1);
                if (s1 < CAPSLOT) list1[e1 * CAPSLOT + s1] = token;
                int s2 = atomicAdd(&count2[e2], 1);
                if (s2 < CAPSLOT) list2[e2 * CAPSLOT + s2] = token;
            }
        }
    }
    grid.sync();

    // =======================================================================
    // Phase B: per-expert ranking (blocks 0..63).
    // rank(t) = #{t' in same list : p1[t'] > p1[t] or (== and t' < t)}
    // keep1: rank1 < CAP.  keep2: rank2 + (pre-drop top1 count) < CAP.
    // =======================================================================
    if (blockIdx.x < EXPERTS) {
        const int e  = blockIdx.x;
        const int n1 = min(count1[e], CAPSLOT);

        for (int i = tid; i < n1; i += 256) {
            int t = list1[e * CAPSLOT + i];
            stok[i] = t;
            skey[i] = p1o[t];
        }
        __syncthreads();
        for (int i = tid; i < n1; i += 256) {
            const float ki = skey[i];
            const int   ti = stok[i];
            int r = 0;
            for (int j = 0; j < n1; ++j)
                r += (skey[j] > ki || (skey[j] == ki && stok[j] < ti)) ? 1 : 0;
            keep1[ti] = (r < CAP) ? 1 : 0;
        }
        __syncthreads();

        const int n2 = min(count2[e], CAPSLOT);
        for (int i = tid; i < n2; i += 256) {
            int t = list2[e * CAPSLOT + i];
            stok[i] = t;
            skey[i] = p1o[t];
        }
        __syncthreads();
        for (int i = tid; i < n2; i += 256) {
            const float ki = skey[i];
            const int   ti = stok[i];
            int r = n1;                      // offset by pre-drop top-1 count
            for (int j = 0; j < n2; ++j)
                r += (skey[j] > ki || (skey[j] == ki && stok[j] < ti)) ? 1 : 0;
            keep2[ti] = (r < CAP) ? 1 : 0;
        }
    }
    grid.sync();

    // =======================================================================
    // Phase C: materialize [top_1_mask | gates]. 16 threads per token row,
    // one float4 per thread per half; 2 slots per thread to cover all rows.
    // =======================================================================
    {
        const int g = blockIdx.x * 256 + tid;        // 0..131071
        #pragma unroll
        for (int rep = 0; rep < 2; ++rep) {
            const int slot  = g + rep * (GRID_BLKS * 256);
            const int token = slot >> 4;
            const int eb    = (slot & 15) * 4;

            const int  k1 = keep1[token];
            const int  k2 = keep2[token];
            const float P1 = k1 ? p1o[token] : 0.0f;
            const float P2 = k2 ? p2o[token] : 0.0f;
            const float denom = fmaxf(P1 + P2, 1.1920929e-07f);  // fp32 eps
            const float g1 = P1 / denom;
            const float g2 = P2 / denom;
            const int e1 = top1o[token];
            const int e2 = top2o[token];

            float4 mv, pv;
            mv.x = (k1 && e1 == eb + 0) ? 1.0f : 0.0f;
            mv.y = (k1 && e1 == eb + 1) ? 1.0f : 0.0f;
            mv.z = (k1 && e1 == eb + 2) ? 1.0f : 0.0f;
            mv.w = (k1 && e1 == eb + 3) ? 1.0f : 0.0f;
            pv.x = (k1 && e1 == eb + 0) ? g1 : ((k2 && e2 == eb + 0) ? g2 : 0.0f);
            pv.y = (k1 && e1 == eb + 1) ? g1 : ((k2 && e2 == eb + 1) ? g2 : 0.0f);
            pv.z = (k1 && e1 == eb + 2) ? g1 : ((k2 && e2 == eb + 2) ? g2 : 0.0f);
            pv.w = (k1 && e1 == eb + 3) ? g1 : ((k2 && e2 == eb + 3) ? g2 : 0.0f);

            *(float4*)(out + (size_t)token * EXPERTS + eb) = mv;
            *(float4*)(out + (size_t)TOKENS * EXPERTS
                           + (size_t)token * EXPERTS + eb) = pv;
        }
    }
}

// ---------------------------------------------------------------------------
extern "C" void kernel_launch(void* const* d_in, const int* in_sizes, int n_in,
                              void* d_out, int out_size, void* d_ws, size_t ws_size,
                              hipStream_t stream)
{
    const float* x = (const float*)d_in[0];   // (8,2048,2048) fp32
    const float* W = (const float*)d_in[1];   // (2048,64) fp32
    float* out = (float*)d_out;               // 2 * 16384 * 64 fp32

    // workspace layout (~0.9 MB)
    char* ws = (char*)d_ws;
    float* p1    = (float*)ws;                            // TOKENS
    float* p2    = p1 + TOKENS;                           // TOKENS
    int*   top1  = (int*)(p2 + TOKENS);                   // TOKENS
    int*   top2  = top1 + TOKENS;                         // TOKENS
    int*   keep1 = top2 + TOKENS;                         // TOKENS
    int*   keep2 = keep1 + TOKENS;                        // TOKENS
    int*   count1 = keep2 + TOKENS;                       // EXPERTS
    int*   count2 = count1 + EXPERTS;                     // EXPERTS
    int*   list1  = count2 + EXPERTS;                     // EXPERTS*CAPSLOT
    int*   list2  = list1 + EXPERTS * CAPSLOT;            // EXPERTS*CAPSLOT

    void* args[] = {
        (void*)&x, (void*)&W, (void*)&out,
        (void*)&p1, (void*)&p2, (void*)&top1, (void*)&top2,
        (void*)&count1, (void*)&count2, (void*)&list1, (void*)&list2,
        (void*)&keep1, (void*)&keep2
    };
    (void)hipLaunchCooperativeKernel((const void*)k_fused,
                                     dim3(GRID_BLKS), dim3(256),
                                     args, 0, stream);
}

// Round 6
// 354.556 us; speedup vs baseline: 1.8824x; 1.8824x over previous
//
#include <hip/hip_runtime.h>
#include <math.h>

// Problem constants (fixed by reference).
#define TOKENS      16384     // 8 * 2048
#define HID         2048
#define EXPERTS     64
#define CAPSLOT     1024      // per-expert list cap; counts ~Binom(16384,1/64)=256±16
#define CAP         512       // expert_capacity = 2*ceil(16384/64)
#define KSPLIT      4
#define KCH         512       // k per chunk (KSPLIT*KCH = HID)

__device__ __forceinline__ void fma8(float* a, float s, float4 w0, float4 w1) {
    a[0] = fmaf(s, w0.x, a[0]); a[1] = fmaf(s, w0.y, a[1]);
    a[2] = fmaf(s, w0.z, a[2]); a[3] = fmaf(s, w0.w, a[3]);
    a[4] = fmaf(s, w1.x, a[4]); a[5] = fmaf(s, w1.y, a[5]);
    a[6] = fmaf(s, w1.z, a[6]); a[7] = fmaf(s, w1.w, a[7]);
}

// ---------------------------------------------------------------------------
// K1: partial logits GEMM. Grid = 64 token-groups x 4 k-chunks = 256 blocks
// (1/CU). Block: W chunk (512 k x 64 e = 128 KB) staged to LDS ONCE (single
// barrier), then a barrier-free K-loop: x per-lane float4 from global
// (in-order vmcnt, prefetch-1, L1 line reuse), W via ds_read_b128 broadcast
// (same-address across 8 lanes = free; 2-way bank alias = free).
// Thread tile: 8 tokens x 8 experts = 64 fp32 acc.
// Also zeroes the per-expert counters (stream-ordered before k_route).
// ---------------------------------------------------------------------------
__global__ __launch_bounds__(256, 1) void k_partial(
    const float* __restrict__ x, const float* __restrict__ W,
    float* __restrict__ partial,
    int* __restrict__ count1, int* __restrict__ count2)
{
    __shared__ float wl[KCH * EXPERTS];   // 128 KB

    const int tid = threadIdx.x;
    if (blockIdx.x == 0) {
        if (tid < EXPERTS)            count1[tid] = 0;
        else if (tid < 2 * EXPERTS)   count2[tid - EXPERTS] = 0;
    }

    const int tb = blockIdx.x & 63;       // token block (256 tokens)
    const int kc = blockIdx.x >> 6;       // k chunk 0..3
    const int k0 = kc * KCH;

    // stage W chunk, coalesced float4 (32 per thread)
    {
        const float4* src = (const float4*)(W + (size_t)k0 * EXPERTS);
        float4* dst = (float4*)wl;
        #pragma unroll
        for (int i = 0; i < (KCH * EXPERTS / 4) / 256; ++i)
            dst[i * 256 + tid] = src[i * 256 + tid];
    }
    __syncthreads();

    const int lane = tid & 63;
    const int wv   = tid >> 6;            // wave 0..3
    const int tg   = lane >> 3;           // token group 0..7
    const int eg   = lane & 7;            // expert group 0..7 (experts 8eg..)
    const int tok0 = tb * 256 + wv * 64 + tg * 8;
    const float* xb = x + (size_t)tok0 * HID + k0;

    float acc[8][8];
    #pragma unroll
    for (int i = 0; i < 8; ++i)
        #pragma unroll
        for (int e = 0; e < 8; ++e) acc[i][e] = 0.f;

    float4 xv[8];
    #pragma unroll
    for (int i = 0; i < 8; ++i)
        xv[i] = *(const float4*)(xb + (size_t)i * HID);

    #pragma unroll 2
    for (int k4 = 0; k4 < KCH; k4 += 4) {
        float4 xn[8];
        const bool more = (k4 + 4 < KCH);
        if (more) {
            #pragma unroll
            for (int i = 0; i < 8; ++i)
                xn[i] = *(const float4*)(xb + (size_t)i * HID + k4 + 4);
        }

        float4 w0[4], w1[4];
        #pragma unroll
        for (int kk = 0; kk < 4; ++kk) {
            const float* wp = &wl[(k4 + kk) * EXPERTS + eg * 8];
            w0[kk] = *(const float4*)wp;
            w1[kk] = *(const float4*)(wp + 4);
        }

        #pragma unroll
        for (int i = 0; i < 8; ++i) {
            fma8(acc[i], xv[i].x, w0[0], w1[0]);
            fma8(acc[i], xv[i].y, w0[1], w1[1]);
            fma8(acc[i], xv[i].z, w0[2], w1[2]);
            fma8(acc[i], xv[i].w, w0[3], w1[3]);
        }

        if (more) {
            #pragma unroll
            for (int i = 0; i < 8; ++i) xv[i] = xn[i];
        }
    }

    float* pb = partial + ((size_t)kc * TOKENS + tok0) * EXPERTS + eg * 8;
    #pragma unroll
    for (int i = 0; i < 8; ++i) {
        *(float4*)(pb + (size_t)i * EXPERTS) =
            make_float4(acc[i][0], acc[i][1], acc[i][2], acc[i][3]);
        *(float4*)(pb + (size_t)i * EXPERTS + 4) =
            make_float4(acc[i][4], acc[i][5], acc[i][6], acc[i][7]);
    }
}

// ---------------------------------------------------------------------------
// K2: reduce k-chunks + softmax + top1/top2 + per-expert list build.
// Wave = 1 token x 64 expert lanes; 4 tokens per 256-thread block.
// ---------------------------------------------------------------------------
__global__ __launch_bounds__(256) void k_route(
    const float* __restrict__ partial,
    float* __restrict__ p1o, float* __restrict__ p2o,
    int* __restrict__ top1o, int* __restrict__ top2o,
    int* __restrict__ count1, int* __restrict__ count2,
    int* __restrict__ list1, int* __restrict__ list2)
{
    const int tid   = threadIdx.x;
    const int e     = tid & 63;
    const int token = blockIdx.x * 4 + (tid >> 6);

    float logit = 0.f;
    #pragma unroll
    for (int c = 0; c < KSPLIT; ++c)
        logit += partial[((size_t)c * TOKENS + token) * EXPERTS + e];

    // top-1 argmax, first-index tie-break
    float bv = logit; int be = e;
    #pragma unroll
    for (int m = 32; m >= 1; m >>= 1) {
        float ov = __shfl_xor(bv, m);
        int   oe = __shfl_xor(be, m);
        if (ov > bv || (ov == bv && oe < be)) { bv = ov; be = oe; }
    }
    const float m1 = bv;
    const int   e1 = be;

    // top-2: argmax excluding e1
    float bv2 = (e == e1) ? -INFINITY : logit;
    int   be2 = (e == e1) ? (1 << 30) : e;
    #pragma unroll
    for (int m = 32; m >= 1; m >>= 1) {
        float ov = __shfl_xor(bv2, m);
        int   oe = __shfl_xor(be2, m);
        if (ov > bv2 || (ov == bv2 && oe < be2)) { bv2 = ov; be2 = oe; }
    }
    const int e2 = be2;

    // softmax denominator (max-subtracted)
    float s = expf(logit - m1);
    #pragma unroll
    for (int m = 32; m >= 1; m >>= 1) s += __shfl_xor(s, m);

    if (e == 0) {
        p1o[token]   = 1.0f / s;
        p2o[token]   = expf(bv2 - m1) / s;
        top1o[token] = e1;
        top2o[token] = e2;
        int s1 = atomicAdd(&count1[e1], 1);
        if (s1 < CAPSLOT) list1[e1 * CAPSLOT + s1] = token;
        int s2 = atomicAdd(&count2[e2], 1);
        if (s2 < CAPSLOT) list2[e2 * CAPSLOT + s2] = token;
    }
}

// ---------------------------------------------------------------------------
// K3: per-expert batch-prioritized ranking -> keep flags.
// rank(t) = #{t' in same list : p1[t'] > p1[t] or (== and t' < t)}
// keep1: rank1 < CAP.  keep2: rank2 + (pre-drop top1 count) < CAP.
// ---------------------------------------------------------------------------
__global__ __launch_bounds__(256) void k_rank(
    const float* __restrict__ p1,
    const int* __restrict__ count1, const int* __restrict__ count2,
    const int* __restrict__ list1, const int* __restrict__ list2,
    int* __restrict__ keep1, int* __restrict__ keep2)
{
    __shared__ float skey[CAPSLOT];
    __shared__ int   stok[CAPSLOT];

    const int e  = blockIdx.x;
    const int n1 = min(count1[e], CAPSLOT);

    for (int i = threadIdx.x; i < n1; i += 256) {
        int t = list1[e * CAPSLOT + i];
        stok[i] = t;
        skey[i] = p1[t];
    }
    __syncthreads();
    for (int i = threadIdx.x; i < n1; i += 256) {
        const float ki = skey[i];
        const int   ti = stok[i];
        int r = 0;
        for (int j = 0; j < n1; ++j)
            r += (skey[j] > ki || (skey[j] == ki && stok[j] < ti)) ? 1 : 0;
        keep1[ti] = (r < CAP) ? 1 : 0;
    }
    __syncthreads();

    const int n2 = min(count2[e], CAPSLOT);
    for (int i = threadIdx.x; i < n2; i += 256) {
        int t = list2[e * CAPSLOT + i];
        stok[i] = t;
        skey[i] = p1[t];
    }
    __syncthreads();
    for (int i = threadIdx.x; i < n2; i += 256) {
        const float ki = skey[i];
        const int   ti = stok[i];
        int r = n1;                        // offset by pre-drop top-1 count
        for (int j = 0; j < n2; ++j)
            r += (skey[j] > ki || (skey[j] == ki && stok[j] < ti)) ? 1 : 0;
        keep2[ti] = (r < CAP) ? 1 : 0;
    }
}

// ---------------------------------------------------------------------------
// K4: materialize [top_1_mask | gates], coalesced (16 threads per token row).
// ---------------------------------------------------------------------------
__global__ __launch_bounds__(256) void k_out(
    const float* __restrict__ p1, const float* __restrict__ p2,
    const int* __restrict__ top1, const int* __restrict__ top2,
    const int* __restrict__ keep1, const int* __restrict__ keep2,
    float* __restrict__ out)
{
    const int tid   = threadIdx.x;
    const int token = blockIdx.x * 16 + (tid >> 4);
    const int eb    = (tid & 15) * 4;

    const int  k1 = keep1[token];
    const int  k2 = keep2[token];
    const float P1 = k1 ? p1[token] : 0.0f;
    const float P2 = k2 ? p2[token] : 0.0f;
    const float denom = fmaxf(P1 + P2, 1.1920929e-07f);   // fp32 eps clip
    const float g1 = P1 / denom;
    const float g2 = P2 / denom;
    const int e1 = top1[token];
    const int e2 = top2[token];

    float4 mv, pv;
    mv.x = (k1 && e1 == eb + 0) ? 1.0f : 0.0f;
    mv.y = (k1 && e1 == eb + 1) ? 1.0f : 0.0f;
    mv.z = (k1 && e1 == eb + 2) ? 1.0f : 0.0f;
    mv.w = (k1 && e1 == eb + 3) ? 1.0f : 0.0f;
    pv.x = (k1 && e1 == eb + 0) ? g1 : ((k2 && e2 == eb + 0) ? g2 : 0.0f);
    pv.y = (k1 && e1 == eb + 1) ? g1 : ((k2 && e2 == eb + 1) ? g2 : 0.0f);
    pv.z = (k1 && e1 == eb + 2) ? g1 : ((k2 && e2 == eb + 2) ? g2 : 0.0f);
    pv.w = (k1 && e1 == eb + 3) ? g1 : ((k2 && e2 == eb + 3) ? g2 : 0.0f);

    *(float4*)(out + (size_t)token * EXPERTS + eb) = mv;
    *(float4*)(out + (size_t)TOKENS * EXPERTS + (size_t)token * EXPERTS + eb) = pv;
}

// ---------------------------------------------------------------------------
extern "C" void kernel_launch(void* const* d_in, const int* in_sizes, int n_in,
                              void* d_out, int out_size, void* d_ws, size_t ws_size,
                              hipStream_t stream)
{
    const float* x = (const float*)d_in[0];   // (8,2048,2048) fp32
    const float* W = (const float*)d_in[1];   // (2048,64) fp32
    float* out = (float*)d_out;               // 2 * 16384 * 64 fp32

    // workspace layout (~17.7 MB, matches R4-proven footprint)
    char* ws = (char*)d_ws;
    float* partial = (float*)ws;                          // KSPLIT*TOKENS*EXPERTS
    float* p1    = partial + (size_t)KSPLIT * TOKENS * EXPERTS;
    float* p2    = p1 + TOKENS;
    int*   top1  = (int*)(p2 + TOKENS);
    int*   top2  = top1 + TOKENS;
    int*   keep1 = top2 + TOKENS;
    int*   keep2 = keep1 + TOKENS;
    int*   count1 = keep2 + TOKENS;                       // EXPERTS
    int*   count2 = count1 + EXPERTS;                     // EXPERTS
    int*   list1  = count2 + EXPERTS;                     // EXPERTS*CAPSLOT
    int*   list2  = list1 + EXPERTS * CAPSLOT;            // EXPERTS*CAPSLOT

    k_partial<<<64 * KSPLIT, 256, 0, stream>>>(x, W, partial, count1, count2);
    k_route<<<TOKENS / 4, 256, 0, stream>>>(
        partial, p1, p2, top1, top2, count1, count2, list1, list2);
    k_rank<<<EXPERTS, 256, 0, stream>>>(
        p1, count1, count2, list1, list2, keep1, keep2);
    k_out<<<TOKENS / 16, 256, 0, stream>>>(
        p1, p2, top1, top2, keep1, keep2, out);
}

// Round 7
// 302.066 us; speedup vs baseline: 2.2095x; 1.1738x over previous
//
#include <hip/hip_runtime.h>
#include <math.h>

// Problem constants (fixed by reference).
#define TOKENS      16384     // 8 * 2048
#define HID         2048
#define EXPERTS     64
#define CAPSLOT     1024      // per-expert list cap; counts ~Binom(16384,1/64)=256±16
#define CAP         512       // expert_capacity = 2*ceil(16384/64)
#define KSPLIT      4
#define KCH         512       // k per chunk (KSPLIT*KCH = HID)

__device__ __forceinline__ void fma8(float* a, float s, float4 w0, float4 w1) {
    a[0] = fmaf(s, w0.x, a[0]); a[1] = fmaf(s, w0.y, a[1]);
    a[2] = fmaf(s, w0.z, a[2]); a[3] = fmaf(s, w0.w, a[3]);
    a[4] = fmaf(s, w1.x, a[4]); a[5] = fmaf(s, w1.y, a[5]);
    a[6] = fmaf(s, w1.z, a[6]); a[7] = fmaf(s, w1.w, a[7]);
}

// ---------------------------------------------------------------------------
// K1: partial logits GEMM. Grid = 64 token-groups x 4 k-chunks = 256 blocks
// (1/CU). W chunk (512 k x 64 e = 128 KB) staged to LDS once (single
// barrier), then a barrier-free K-loop: x per-lane float4 from global
// (in-order vmcnt, prefetch-1, L1 line reuse), W via ds_read_b128 broadcast.
// Thread tile: 8 tokens x 8 experts = 64 fp32 acc.
// ---------------------------------------------------------------------------
__global__ __launch_bounds__(256, 1) void k_partial(
    const float* __restrict__ x, const float* __restrict__ W,
    float* __restrict__ partial)
{
    __shared__ float wl[KCH * EXPERTS];   // 128 KB

    const int tid = threadIdx.x;
    const int tb = blockIdx.x & 63;       // token block (256 tokens)
    const int kc = blockIdx.x >> 6;       // k chunk 0..3
    const int k0 = kc * KCH;

    // stage W chunk, coalesced float4 (32 per thread)
    {
        const float4* src = (const float4*)(W + (size_t)k0 * EXPERTS);
        float4* dst = (float4*)wl;
        #pragma unroll
        for (int i = 0; i < (KCH * EXPERTS / 4) / 256; ++i)
            dst[i * 256 + tid] = src[i * 256 + tid];
    }
    __syncthreads();

    const int lane = tid & 63;
    const int wv   = tid >> 6;            // wave 0..3
    const int tg   = lane >> 3;           // token group 0..7
    const int eg   = lane & 7;            // expert group 0..7 (experts 8eg..)
    const int tok0 = tb * 256 + wv * 64 + tg * 8;
    const float* xb = x + (size_t)tok0 * HID + k0;

    float acc[8][8];
    #pragma unroll
    for (int i = 0; i < 8; ++i)
        #pragma unroll
        for (int e = 0; e < 8; ++e) acc[i][e] = 0.f;

    float4 xv[8];
    #pragma unroll
    for (int i = 0; i < 8; ++i)
        xv[i] = *(const float4*)(xb + (size_t)i * HID);

    #pragma unroll 2
    for (int k4 = 0; k4 < KCH; k4 += 4) {
        float4 xn[8];
        const bool more = (k4 + 4 < KCH);
        if (more) {
            #pragma unroll
            for (int i = 0; i < 8; ++i)
                xn[i] = *(const float4*)(xb + (size_t)i * HID + k4 + 4);
        }

        float4 w0[4], w1[4];
        #pragma unroll
        for (int kk = 0; kk < 4; ++kk) {
            const float* wp = &wl[(k4 + kk) * EXPERTS + eg * 8];
            w0[kk] = *(const float4*)wp;
            w1[kk] = *(const float4*)(wp + 4);
        }

        #pragma unroll
        for (int i = 0; i < 8; ++i) {
            fma8(acc[i], xv[i].x, w0[0], w1[0]);
            fma8(acc[i], xv[i].y, w0[1], w1[1]);
            fma8(acc[i], xv[i].z, w0[2], w1[2]);
            fma8(acc[i], xv[i].w, w0[3], w1[3]);
        }

        if (more) {
            #pragma unroll
            for (int i = 0; i < 8; ++i) xv[i] = xn[i];
        }
    }

    float* pb = partial + ((size_t)kc * TOKENS + tok0) * EXPERTS + eg * 8;
    #pragma unroll
    for (int i = 0; i < 8; ++i) {
        *(float4*)(pb + (size_t)i * EXPERTS) =
            make_float4(acc[i][0], acc[i][1], acc[i][2], acc[i][3]);
        *(float4*)(pb + (size_t)i * EXPERTS + 4) =
            make_float4(acc[i][4], acc[i][5], acc[i][6], acc[i][7]);
    }
}

// ---------------------------------------------------------------------------
// K2: reduce k-chunks + softmax + top1/top2. NO atomics, no lists — just
// 4 coalesced stores per token. Wave = 1 token x 64 expert lanes.
// ---------------------------------------------------------------------------
__global__ __launch_bounds__(256) void k_route(
    const float* __restrict__ partial,
    float* __restrict__ p1o, float* __restrict__ p2o,
    int* __restrict__ top1o, int* __restrict__ top2o)
{
    const int tid   = threadIdx.x;
    const int e     = tid & 63;
    const int token = blockIdx.x * 4 + (tid >> 6);

    float logit = 0.f;
    #pragma unroll
    for (int c = 0; c < KSPLIT; ++c)
        logit += partial[((size_t)c * TOKENS + token) * EXPERTS + e];

    // top-1 argmax, first-index tie-break
    float bv = logit; int be = e;
    #pragma unroll
    for (int m = 32; m >= 1; m >>= 1) {
        float ov = __shfl_xor(bv, m);
        int   oe = __shfl_xor(be, m);
        if (ov > bv || (ov == bv && oe < be)) { bv = ov; be = oe; }
    }
    const float m1 = bv;
    const int   e1 = be;

    // top-2: argmax excluding e1
    float bv2 = (e == e1) ? -INFINITY : logit;
    int   be2 = (e == e1) ? (1 << 30) : e;
    #pragma unroll
    for (int m = 32; m >= 1; m >>= 1) {
        float ov = __shfl_xor(bv2, m);
        int   oe = __shfl_xor(be2, m);
        if (ov > bv2 || (ov == bv2 && oe < be2)) { bv2 = ov; be2 = oe; }
    }
    const int e2 = be2;

    // softmax denominator (max-subtracted)
    float s = expf(logit - m1);
    #pragma unroll
    for (int m = 32; m >= 1; m >>= 1) s += __shfl_xor(s, m);

    if (e == 0) {
        p1o[token]   = 1.0f / s;
        p2o[token]   = expf(bv2 - m1) / s;
        top1o[token] = e1;
        top2o[token] = e2;
    }
}

// ---------------------------------------------------------------------------
// K3: per-expert batch-prioritized ranking -> keep flags. One block per
// expert scans ALL tokens (top1/p1 are 128 KB total -> L2/L1-hot; the 64x
// redundancy is cheap), builds its list in LDS with block-local atomics
// (no cross-block contention), then O(n^2) rank.
// rank(t) = #{t' in same list : p1[t'] > p1[t] or (== and t' < t)}
// keep1: rank1 < CAP.  keep2: rank2 + n1_raw (pre-drop top1 count) < CAP.
// ---------------------------------------------------------------------------
__global__ __launch_bounds__(256) void k_rank(
    const float* __restrict__ p1,
    const int* __restrict__ top1, const int* __restrict__ top2,
    int* __restrict__ keep1, int* __restrict__ keep2)
{
    __shared__ float skey[CAPSLOT];
    __shared__ int   stok[CAPSLOT];
    __shared__ int   cnt;

    const int e   = blockIdx.x;
    const int tid = threadIdx.x;

    // ---- scan for top-1 == e ----
    if (tid == 0) cnt = 0;
    __syncthreads();
    for (int t = tid; t < TOKENS; t += 256) {
        if (top1[t] == e) {
            int i = atomicAdd(&cnt, 1);
            if (i < CAPSLOT) { stok[i] = t; skey[i] = p1[t]; }
        }
    }
    __syncthreads();
    const int n1_raw = cnt;
    const int n1 = min(n1_raw, CAPSLOT);

    for (int i = tid; i < n1; i += 256) {
        const float ki = skey[i];
        const int   ti = stok[i];
        int r = 0;
        for (int j = 0; j < n1; ++j)
            r += (skey[j] > ki || (skey[j] == ki && stok[j] < ti)) ? 1 : 0;
        keep1[ti] = (r < CAP) ? 1 : 0;
    }
    __syncthreads();

    // ---- scan for top-2 == e ----
    if (tid == 0) cnt = 0;
    __syncthreads();
    for (int t = tid; t < TOKENS; t += 256) {
        if (top2[t] == e) {
            int i = atomicAdd(&cnt, 1);
            if (i < CAPSLOT) { stok[i] = t; skey[i] = p1[t]; }
        }
    }
    __syncthreads();
    const int n2 = min(cnt, CAPSLOT);

    for (int i = tid; i < n2; i += 256) {
        const float ki = skey[i];
        const int   ti = stok[i];
        int r = n1_raw;                    // offset by pre-drop top-1 count
        for (int j = 0; j < n2; ++j)
            r += (skey[j] > ki || (skey[j] == ki && stok[j] < ti)) ? 1 : 0;
        keep2[ti] = (r < CAP) ? 1 : 0;
    }
}

// ---------------------------------------------------------------------------
// K4: materialize [top_1_mask | gates], coalesced (16 threads per token row).
// ---------------------------------------------------------------------------
__global__ __launch_bounds__(256) void k_out(
    const float* __restrict__ p1, const float* __restrict__ p2,
    const int* __restrict__ top1, const int* __restrict__ top2,
    const int* __restrict__ keep1, const int* __restrict__ keep2,
    float* __restrict__ out)
{
    const int tid   = threadIdx.x;
    const int token = blockIdx.x * 16 + (tid >> 4);
    const int eb    = (tid & 15) * 4;

    const int  k1 = keep1[token];
    const int  k2 = keep2[token];
    const float P1 = k1 ? p1[token] : 0.0f;
    const float P2 = k2 ? p2[token] : 0.0f;
    const float denom = fmaxf(P1 + P2, 1.1920929e-07f);   // fp32 eps clip
    const float g1 = P1 / denom;
    const float g2 = P2 / denom;
    const int e1 = top1[token];
    const int e2 = top2[token];

    float4 mv, pv;
    mv.x = (k1 && e1 == eb + 0) ? 1.0f : 0.0f;
    mv.y = (k1 && e1 == eb + 1) ? 1.0f : 0.0f;
    mv.z = (k1 && e1 == eb + 2) ? 1.0f : 0.0f;
    mv.w = (k1 && e1 == eb + 3) ? 1.0f : 0.0f;
    pv.x = (k1 && e1 == eb + 0) ? g1 : ((k2 && e2 == eb + 0) ? g2 : 0.0f);
    pv.y = (k1 && e1 == eb + 1) ? g1 : ((k2 && e2 == eb + 1) ? g2 : 0.0f);
    pv.z = (k1 && e1 == eb + 2) ? g1 : ((k2 && e2 == eb + 2) ? g2 : 0.0f);
    pv.w = (k1 && e1 == eb + 3) ? g1 : ((k2 && e2 == eb + 3) ? g2 : 0.0f);

    *(float4*)(out + (size_t)token * EXPERTS + eb) = mv;
    *(float4*)(out + (size_t)TOKENS * EXPERTS + (size_t)token * EXPERTS + eb) = pv;
}

// ---------------------------------------------------------------------------
extern "C" void kernel_launch(void* const* d_in, const int* in_sizes, int n_in,
                              void* d_out, int out_size, void* d_ws, size_t ws_size,
                              hipStream_t stream)
{
    const float* x = (const float*)d_in[0];   // (8,2048,2048) fp32
    const float* W = (const float*)d_in[1];   // (2048,64) fp32
    float* out = (float*)d_out;               // 2 * 16384 * 64 fp32

    // workspace layout (~17.2 MB)
    char* ws = (char*)d_ws;
    float* partial = (float*)ws;                          // KSPLIT*TOKENS*EXPERTS
    float* p1    = partial + (size_t)KSPLIT * TOKENS * EXPERTS;
    float* p2    = p1 + TOKENS;
    int*   top1  = (int*)(p2 + TOKENS);
    int*   top2  = top1 + TOKENS;
    int*   keep1 = top2 + TOKENS;
    int*   keep2 = keep1 + TOKENS;

    k_partial<<<64 * KSPLIT, 256, 0, stream>>>(x, W, partial);
    k_route<<<TOKENS / 4, 256, 0, stream>>>(partial, p1, p2, top1, top2);
    k_rank<<<EXPERTS, 256, 0, stream>>>(p1, top1, top2, keep1, keep2);
    k_out<<<TOKENS / 16, 256, 0, stream>>>(
        p1, p2, top1, top2, keep1, keep2, out);
}